// Round 10
// baseline (53.829 us; speedup 1.0000x reference)
//
#include <hip/hip_runtime.h>

// Triplet generation (DimeNet-style) for constant-degree graph.
// Outputs (concatenated in d_out as float32): id3_i, id3_j, id3_k,
// distances_jk, angles, mask — each num_nodes*DEG*DEG elements.
//
// R10: two 16-node chunks per block (1563 WGs). Chunk B's gather is
// issued into registers before chunk A's compute and published to a
// second LDS buffer; the inter-chunk barrier is a raw
// s_waitcnt lgkmcnt(0) + s_barrier (NO vmcnt drain), so chunk A's
// global stores remain in flight under chunk B's compute.

#define DEG 16
#define NPB 16                     // nodes per chunk
#define THREADS (NPB * 64)         // 1024
#define CUTOFF_F 5.0f

typedef float f32x4 __attribute__((ext_vector_type(4)));

// fast atan2 for y >= 0: result in [0, pi]; atan2(0, 0) -> 0 (matches numpy).
__device__ __forceinline__ float fast_atan2_pos(float y, float x) {
    const float PI_F   = 3.14159274f;
    const float PIO2_F = 1.57079637f;
    const float ax = fabsf(x);
    const float mn = fminf(ax, y);
    const float mx = fmaxf(ax, y);
    const float a = (mx > 0.0f) ? __fdividef(mn, mx) : 0.0f;
    const float s = a * a;
    float r = fmaf(s, fmaf(s, fmaf(s, fmaf(s, 0.0208351f, -0.085133f),
                                   0.180141f), -0.3302995f), 0.9998660f);
    r *= a;
    if (y > ax)    r = PIO2_F - r;
    if (x < 0.0f)  r = PI_F - r;
    return r;
}

__device__ __forceinline__ void compute_store(
    const float* __restrict__ sx, const float* __restrict__ sy,
    const float* __restrict__ sz, const float* __restrict__ scolf,
    const int* __restrict__ sval,
    int node, int num_nodes, int w, int lane,
    float* __restrict__ out, int P)
{
    if (node >= num_nodes) return;   // no barriers below: early-out is safe

    const int ofs = w * DEG;
    const int j = lane >> 2;
    const int k0 = (lane & 3) << 2;

    const float jx = sx[ofs + j], jy = sy[ofs + j], jz = sz[ofs + j];
    const int   jv = sval[ofs + j];
    const float jcolf = scolf[ofs + j];

    f32x4 o_k, o_d, o_a, o_m;

    #pragma unroll
    for (int q = 0; q < 4; ++q) {
        const int k = k0 + q;
        const float kx = sx[ofs + k], ky = sy[ofs + k], kz = sz[ofs + k];
        const int   kv = sval[ofs + k];
        const bool m = (jv != 0) && (kv != 0) && (j != k);

        // angle(j,i,k) = atan2(|R1_j x R1_k|, R1_j . R1_k)
        const float dot = jx * kx + jy * ky + jz * kz;
        const float cx = jy * kz - jz * ky;
        const float cy = jz * kx - jx * kz;
        const float cz = jx * ky - jy * kx;
        const float cn2 = cx * cx + cy * cy + cz * cz;
        const float ang = m ? fast_atan2_pos(sqrtf(cn2), dot) : 0.0f;

        // |R1_j - R1_k| with the reference's d2==0 -> 1.0 quirk
        const float dx = jx - kx, dy = jy - ky, dz = jz - kz;
        const float d2 = dx * dx + dy * dy + dz * dz;
        const float dist = m ? sqrtf(d2 > 0.0f ? d2 : 1.0f) : 0.0f;

        o_k[q] = scolf[ofs + k];
        o_d[q] = dist;
        o_a[q] = ang;
        o_m[q] = m ? 1.0f : 0.0f;
    }

    const int idx = node * (DEG * DEG) + lane * 4;   // < 12.8M, int-safe
    const float fi = (float)node;
    f32x4 o_i; o_i[0] = fi; o_i[1] = fi; o_i[2] = fi; o_i[3] = fi;
    f32x4 o_j; o_j[0] = jcolf; o_j[1] = jcolf; o_j[2] = jcolf; o_j[3] = jcolf;

    float* o0 = out + idx;
    *reinterpret_cast<f32x4*>(o0)         = o_i;
    *reinterpret_cast<f32x4*>(o0 + P)     = o_j;
    *reinterpret_cast<f32x4*>(o0 + 2 * P) = o_k;
    *reinterpret_cast<f32x4*>(o0 + 3 * P) = o_d;
    *reinterpret_cast<f32x4*>(o0 + 4 * P) = o_a;
    *reinterpret_cast<f32x4*>(o0 + 5 * P) = o_m;
}

__global__ __launch_bounds__(THREADS) void triplet_kernel(
    const float* __restrict__ pos,       // [N,3]
    const int* __restrict__ col_idx,     // edge_index[1], length N*DEG
    float* __restrict__ out,             // f32, 6 arrays of P each
    int num_nodes, int P)
{
    // double-buffered staging: [chunk][node*16 + slot]
    __shared__ float sx[2][256], sy[2][256], sz[2][256], scolf[2][256];
    __shared__ int   sval[2][256];

    const int tid = threadIdx.x;
    const int w = tid >> 6;
    const int lane = tid & 63;
    const int baseA = blockIdx.x * (2 * NPB);
    const int baseB = baseA + NPB;

    const int nl = tid >> 4;           // stager: local node
    const int slot = tid & 15;         // stager: neighbor slot
    const bool stager = (tid < 256);
    const int nodeB = baseB + nl;
    const bool haveB = stager && (nodeB < num_nodes);

    // Prefetch chunk B's neighbor ids early (latency hides under chunk A staging).
    int cB = 0;
    if (haveB) cB = col_idx[nodeB * DEG + slot];

    // Stage chunk A.
    if (stager) {
        const int nodeA = baseA + nl;
        if (nodeA < num_nodes) {
            const int c = col_idx[nodeA * DEG + slot];
            const float px = pos[3 * nodeA], py = pos[3 * nodeA + 1], pz = pos[3 * nodeA + 2];
            const float rx = pos[3 * c]     - px;
            const float ry = pos[3 * c + 1] - py;
            const float rz = pos[3 * c + 2] - pz;
            const float d = sqrtf(rx * rx + ry * ry + rz * rz);
            sx[0][tid] = rx; sy[0][tid] = ry; sz[0][tid] = rz;
            scolf[0][tid] = (float)c;
            sval[0][tid] = (d <= CUTOFF_F) ? 1 : 0;
        }
    }
    __syncthreads();

    // Issue chunk B's pos loads into registers now; math deferred to publish
    // so the vmcnt wait lands after chunk A's compute.
    float pxB, pyB, pzB, nxB, nyB, nzB;
    if (haveB) {
        pxB = pos[3 * nodeB]; pyB = pos[3 * nodeB + 1]; pzB = pos[3 * nodeB + 2];
        nxB = pos[3 * cB];    nyB = pos[3 * cB + 1];    nzB = pos[3 * cB + 2];
    }

    // Compute + store chunk A (24 global stores issued, left in flight).
    compute_store(&sx[0][0], &sy[0][0], &sz[0][0], &scolf[0][0], &sval[0][0],
                  baseA + w, num_nodes, w, lane, out, P);

    // Publish chunk B staging into buffer 1.
    if (haveB) {
        const float rx = nxB - pxB, ry = nyB - pyB, rz = nzB - pzB;
        const float d = sqrtf(rx * rx + ry * ry + rz * rz);
        sx[1][tid] = rx; sy[1][tid] = ry; sz[1][tid] = rz;
        scolf[1][tid] = (float)cB;
        sval[1][tid] = (d <= CUTOFF_F) ? 1 : 0;
    }
    // Raw barrier: wait own LDS ops, sync waves — but do NOT drain vmcnt,
    // so chunk A's stores stay in flight under chunk B's compute.
    asm volatile("s_waitcnt lgkmcnt(0)\n\ts_barrier" ::: "memory");

    // Compute + store chunk B.
    compute_store(&sx[1][0], &sy[1][0], &sz[1][0], &scolf[1][0], &sval[1][0],
                  baseB + w, num_nodes, w, lane, out, P);
}

extern "C" void kernel_launch(void* const* d_in, const int* in_sizes, int n_in,
                              void* d_out, int out_size, void* d_ws, size_t ws_size,
                              hipStream_t stream) {
    const float* pos = (const float*)d_in[0];
    const int* edge_index = (const int*)d_in[1];

    const int num_nodes = in_sizes[0] / 3;
    const int E = in_sizes[1] / 2;          // edge_index is [2, E]
    const int* col = edge_index + E;        // row 1 = neighbor ids

    const int P = num_nodes * (DEG * DEG);  // 12.8M, int-safe
    const int blocks = (num_nodes + 2 * NPB - 1) / (2 * NPB);

    triplet_kernel<<<blocks, THREADS, 0, stream>>>(
        pos, col, (float*)d_out, num_nodes, P);
}